// Round 1
// 440.787 us; speedup vs baseline: 1.0559x; 1.0559x over previous
//
#include <hip/hip_runtime.h>
#include <math.h>

// Problem constants
constexpr int kB  = 64;
constexpr int kT  = 2048;
constexpr int kE  = 512;
constexpr int kR  = 1024;
constexpr int kH  = 8;
constexpr int kHD = 16;
constexpr int kNF = 32;
constexpr int kKS = 31;
constexpr float kScale = 0.25f;          // 1/sqrt(16)
constexpr float kCplx  = 0.1f;
constexpr int kChunks = 16;              // t-chunks per b (128 t each)

// Workspace layout (float offsets)
constexpr size_t OFF_WQE  = 0;                            // [B,H,E]     32768
constexpr size_t OFF_CQ   = OFF_WQE + kB * kH * kE;       // [B,H]       512
constexpr size_t OFF_KEFF = OFF_CQ + kB * kH;             // [B,H,2*KS]  31744
constexpr size_t OFF_SC   = OFF_KEFF + kB * kH * 2 * kKS; // [B,T,H] exp 1048576
constexpr size_t OFF_PART = OFF_SC + (size_t)kB * kT * kH;   // [B,16,H,E] 4194304
constexpr size_t OFF_ZP   = OFF_PART + (size_t)kB * kChunks * kH * kE; // [B,16,H] 8192

__device__ __forceinline__ float bcast_lane(float v, int lane) {
    return __uint_as_float((unsigned)__builtin_amdgcn_readlane((int)__float_as_uint(v), lane));
}

// ---------------------------------------------------------------------------
// P: per (b,h) fold query through all weight paths (Wq -> Wk/bk/Wl/conv).
// grid = B*H, block = 256
__global__ __launch_bounds__(256) void k_prep(
    const float* __restrict__ query, const float* __restrict__ Wq,
    const float* __restrict__ bq, const float* __restrict__ Wk,
    const float* __restrict__ bk, const float* __restrict__ Wl,
    const float* __restrict__ convw,
    float* __restrict__ wqe, float* __restrict__ cq, float* __restrict__ keff) {
    int bh = blockIdx.x;
    int b = bh >> 3, h = bh & 7;
    int tid = threadIdx.x;

    // q_s padded: segment p lives at p*65 (addr 64p+i was bank i%32 for ALL
    // 16 p-groups -> 16-way conflict; pad kills it)
    __shared__ float q_s[16 * 65];
    __shared__ float part[kHD][17];
    __shared__ float qd[kHD];
    __shared__ float wl_s[kNF];

    for (int i = tid; i < kR; i += 256)
        q_s[(i >> 6) * 65 + (i & 63)] = query[(size_t)b * kR + i];
    __syncthreads();

    {
        int d = tid >> 4, p = tid & 15;
        const float* wrow = Wq + (size_t)(h * kHD + d) * kR + p * 64;
        const float* qrow = q_s + p * 65;
        float pa = 0.f;
        #pragma unroll 8
        for (int i = 0; i < 64; ++i) pa += wrow[i] * qrow[i];
        part[d][p] = pa;
    }
    __syncthreads();
    if (tid < kHD) {
        float acc = bq[h * kHD + tid];
        #pragma unroll
        for (int p = 0; p < 16; ++p) acc += part[tid][p];
        qd[tid] = acc;
    }
    __syncthreads();

    for (int e = tid; e < kE; e += 256) {
        float acc = 0.f;
        #pragma unroll
        for (int d = 0; d < kHD; ++d) acc += qd[d] * Wk[(size_t)(h * kHD + d) * kE + e];
        wqe[(size_t)bh * kE + e] = acc;
    }
    if (tid < kNF) {
        float acc = 0.f;
        #pragma unroll
        for (int d = 0; d < kHD; ++d) acc += qd[d] * Wl[(h * kHD + d) * kNF + tid];
        wl_s[tid] = acc;
    }
    if (tid == 0) {
        float acc = 0.f;
        #pragma unroll
        for (int d = 0; d < kHD; ++d) acc += qd[d] * bk[h * kHD + d];
        cq[bh] = acc;
    }
    __syncthreads();
    if (tid < 2 * kKS) {
        float acc = 0.f;
        #pragma unroll
        for (int f = 0; f < kNF; ++f) acc += wl_s[f] * convw[f * 2 * kKS + tid];
        keff[bh * 2 * kKS + tid] = acc;
    }
}

// ---------------------------------------------------------------------------
// S: fused scores + exp + per-chunk context partials. ONE pass over memory.
//   sc[b][t][h]        = exp(score)                (no max-sub; |s| <~ 2)
//   part[b][blk][h][e] = sum_{t in blk} exp(s_th) * mem[b,t,e]
//   zp[b][blk][h]      = sum_{t in blk} exp(s_th)
// grid = (16, B), block = 256 (4 waves); block covers 128 t.
// launch_bounds(256,2): cap 256 VGPR -> >=2 waves/SIMD (2 blocks/CU).
__global__ __launch_bounds__(256, 2) void k_scores(
    const float* __restrict__ mem, const float* __restrict__ awc,
    const float* __restrict__ wqe, const float* __restrict__ cq,
    const float* __restrict__ keff, float* __restrict__ sc,
    float* __restrict__ part, float* __restrict__ zp) {
    constexpr int WIN = 128 + kKS - 1;   // 158
    int b = blockIdx.y;
    int blk = blockIdx.x;
    int t0 = blk * 128;
    int tid = threadIdx.x;
    int wave = tid >> 6, lane = tid & 63;

    __shared__ float aw[2][WIN];
    __shared__ float ke[kH][2 * kKS];
    __shared__ float cq_s[kH];
    __shared__ float loc_s[128][9];          // +1 pad
    __shared__ float obh_s[kH][kE];          // 16 KB block accumulator
    __shared__ float zp_s[4][kH];

    for (int i = tid; i < 2 * WIN; i += 256) {
        int c = i / WIN, j = i % WIN;
        int t = t0 - (kKS - 1) / 2 + j;
        aw[c][j] = (t >= 0 && t < kT) ? awc[((size_t)b * 2 + c) * kT + t] : 0.f;
    }
    for (int i = tid; i < kH * 2 * kKS; i += 256)
        ke[i / (2 * kKS)][i % (2 * kKS)] = keff[(size_t)b * kH * 2 * kKS + i];
    if (tid < kH) cq_s[tid] = cq[b * kH + tid];
    for (int i = tid; i < kH * kE; i += 256) ((float*)obh_s)[i] = 0.f;
    __syncthreads();

    // location FIR: all 256 threads (t = tid&127, head-half = tid>>7)
    {
        int tt = tid & 127;
        int hg = (tid >> 7) << 2;            // 0 or 4
        float a0 = 0.f, a1 = 0.f, a2 = 0.f, a3 = 0.f;
        #pragma unroll
        for (int c = 0; c < 2; ++c) {
            #pragma unroll
            for (int k = 0; k < kKS; ++k) {
                float a = aw[c][tt + k];
                a0 += ke[hg + 0][c * kKS + k] * a;
                a1 += ke[hg + 1][c * kKS + k] * a;
                a2 += ke[hg + 2][c * kKS + k] * a;
                a3 += ke[hg + 3][c * kKS + k] * a;
            }
        }
        loc_s[tt][hg + 0] = a0;
        loc_s[tt][hg + 1] = a1;
        loc_s[tt][hg + 2] = a2;
        loc_s[tt][hg + 3] = a3;
    }

    // per-wave content weights: lane holds e = 4*lane..+3 and 256+4*lane..+3
    float w[kH][8];
    {
        const float* wq_b = wqe + (size_t)b * kH * kE;
        #pragma unroll
        for (int h = 0; h < kH; ++h) {
            const float4* p = (const float4*)(wq_b + h * kE);
            float4 x = p[lane];
            float4 y = p[64 + lane];
            w[h][0] = x.x; w[h][1] = x.y; w[h][2] = x.z; w[h][3] = x.w;
            w[h][4] = y.x; w[h][5] = y.y; w[h][6] = y.z; w[h][7] = y.w;
        }
    }
    float acc[kH][8];
    #pragma unroll
    for (int h = 0; h < kH; ++h)
        #pragma unroll
        for (int j = 0; j < 8; ++j) acc[h][j] = 0.f;
    float zacc = 0.f;
    __syncthreads();

    // main loop: 2 rows per iteration + next-pair prefetch (8 float4 loads in
    // flight/lane during compute); two independent shuffle chains interleave.
    const float4* m4 = (const float4*)(mem + ((size_t)b * kT + t0 + wave * 32) * kE);
    float4 x0 = m4[lane],        y0 = m4[64 + lane];
    float4 x1 = m4[128 + lane],  y1 = m4[192 + lane];
    for (int r = 0; r < 32; r += 2) {
        // prefetch next pair; (r+2)&31 wraps to rows 0/1 on last iter (in-bounds,
        // L1-hot, result discarded) -> branch-free
        const float4* mn = m4 + ((r + 2) & 31) * 128;
        float4 nx0 = mn[lane],       ny0 = mn[64 + lane];
        float4 nx1 = mn[128 + lane], ny1 = mn[192 + lane];

        float v0[kH], v1[kH];
        #pragma unroll
        for (int h = 0; h < kH; ++h) {
            v0[h] = x0.x * w[h][0] + x0.y * w[h][1] + x0.z * w[h][2] + x0.w * w[h][3]
                  + y0.x * w[h][4] + y0.y * w[h][5] + y0.z * w[h][6] + y0.w * w[h][7];
            v1[h] = x1.x * w[h][0] + x1.y * w[h][1] + x1.z * w[h][2] + x1.w * w[h][3]
                  + y1.x * w[h][4] + y1.y * w[h][5] + y1.z * w[h][6] + y1.w * w[h][7];
        }
        // scatter-reduce 8->4->2->1 over xor {1,2,4}, then butterfly 8,16,32
        #pragma unroll
        for (int s = 0; s < 3; ++s) {
            int m = 1 << s;
            int bit = (lane >> s) & 1;
            #pragma unroll
            for (int i = 0; i < (8 >> (s + 1)); ++i) {
                float k0 = v0[2 * i + bit];
                float o0 = v0[2 * i + (1 - bit)];
                v0[i] = k0 + __shfl_xor(o0, m, 64);
                float k1 = v1[2 * i + bit];
                float o1 = v1[2 * i + (1 - bit)];
                v1[i] = k1 + __shfl_xor(o1, m, 64);
            }
        }
        float r0 = v0[0], r1 = v1[0];
        r0 += __shfl_xor(r0, 8, 64);   r1 += __shfl_xor(r1, 8, 64);
        r0 += __shfl_xor(r0, 16, 64);  r1 += __shfl_xor(r1, 16, 64);
        r0 += __shfl_xor(r0, 32, 64);  r1 += __shfl_xor(r1, 32, 64);
        // every lane now holds the full sum for head (lane&7)
        int hh = lane & 7;
        int wr = wave * 32 + r;
        float s0 = kScale * (r0 + cq_s[hh] + kCplx * loc_s[wr][hh]);
        float s1 = kScale * (r1 + cq_s[hh] + kCplx * loc_s[wr + 1][hh]);
        float ex0 = __expf(s0);
        float ex1 = __expf(s1);
        if (lane < kH) {
            size_t tbase = ((size_t)b * kT + t0 + wave * 32 + r) * kH;
            sc[tbase + lane] = ex0;
            sc[tbase + kH + lane] = ex1;
        }
        zacc += ex0 + ex1;  // lane's head = lane&7 (8 identical copies per head)
        // readlane -> SGPR broadcast; folds into v_fma as scalar operand
        #pragma unroll
        for (int h = 0; h < kH; ++h) {
            float pa = bcast_lane(ex0, h);
            float pb = bcast_lane(ex1, h);
            acc[h][0] += pa * x0.x; acc[h][1] += pa * x0.y;
            acc[h][2] += pa * x0.z; acc[h][3] += pa * x0.w;
            acc[h][4] += pa * y0.x; acc[h][5] += pa * y0.y;
            acc[h][6] += pa * y0.z; acc[h][7] += pa * y0.w;
            acc[h][0] += pb * x1.x; acc[h][1] += pb * x1.y;
            acc[h][2] += pb * x1.z; acc[h][3] += pb * x1.w;
            acc[h][4] += pb * y1.x; acc[h][5] += pb * y1.y;
            acc[h][6] += pb * y1.z; acc[h][7] += pb * y1.w;
        }
        x0 = nx0; y0 = ny0; x1 = nx1; y1 = ny1;
    }
    if (lane < kH) zp_s[wave][lane] = zacc;

    // sequential per-wave accumulation into obh_s (race-free within a wave:
    // lane l covers e = 4l..4l+3 and 256+4l..256+4l+3, disjoint across lanes)
    for (int wv = 0; wv < 4; ++wv) {
        __syncthreads();
        if (wave == wv) {
            #pragma unroll
            for (int h = 0; h < kH; ++h) {
                obh_s[h][4 * lane + 0] += acc[h][0];
                obh_s[h][4 * lane + 1] += acc[h][1];
                obh_s[h][4 * lane + 2] += acc[h][2];
                obh_s[h][4 * lane + 3] += acc[h][3];
                obh_s[h][256 + 4 * lane + 0] += acc[h][4];
                obh_s[h][256 + 4 * lane + 1] += acc[h][5];
                obh_s[h][256 + 4 * lane + 2] += acc[h][6];
                obh_s[h][256 + 4 * lane + 3] += acc[h][7];
            }
        }
    }
    __syncthreads();

    float* pdst = part + ((size_t)(b * kChunks + blk) * kH) * kE;
    for (int i = tid; i < kH * kE; i += 256) pdst[i] = ((float*)obh_s)[i];
    if (tid < kH) {
        float z = zp_s[0][tid] + zp_s[1][tid] + zp_s[2][tid] + zp_s[3][tid];
        zp[(size_t)(b * kChunks + blk) * kH + tid] = z;
    }
}

// ---------------------------------------------------------------------------
// F: finalize. Z_h = sum_blk zp; context[b,e] = (1/8) sum_h O_h[e]/Z_h;
//    fw[b,t] = (1/8) sum_h sc[b,t,h]/Z_h.
// grid = (5, B): sec 0 -> ctx, sec 1..4 -> fw quarter (512 t each).
// 320 blocks (was 64) -> covers far more CUs; the 20 MB reread is latency-bound.
__global__ __launch_bounds__(256) void k_final(
    const float* __restrict__ part, const float* __restrict__ zp,
    const float* __restrict__ sc, float* __restrict__ ctx,
    float* __restrict__ fw) {
    int b = blockIdx.y, sec = blockIdx.x, tid = threadIdx.x;
    __shared__ float rz_s[kH];
    if (tid < kH) {
        float z = 0.f;
        for (int blk = 0; blk < kChunks; ++blk)
            z += zp[(size_t)(b * kChunks + blk) * kH + tid];
        rz_s[tid] = 1.f / z;
    }
    __syncthreads();

    if (sec == 0) {
        const float* pb = part + (size_t)b * kChunks * kH * kE;
        #pragma unroll
        for (int i = 0; i < 2; ++i) {
            int e = tid + i * 256;
            float s = 0.f;
            #pragma unroll
            for (int h = 0; h < kH; ++h) {
                float oh = 0.f;
                for (int blk = 0; blk < kChunks; ++blk)
                    oh += pb[((size_t)blk * kH + h) * kE + e];
                s += oh * rz_s[h];
            }
            ctx[(size_t)b * kE + e] = 0.125f * s;
        }
    } else {
        int tb = (sec - 1) * 512;
        #pragma unroll
        for (int i = 0; i < 2; ++i) {
            int t = tb + tid + i * 256;
            const float4* p = (const float4*)(sc + ((size_t)b * kT + t) * kH);
            float4 x = p[0], y = p[1];
            float f = x.x * rz_s[0] + x.y * rz_s[1] + x.z * rz_s[2] + x.w * rz_s[3]
                    + y.x * rz_s[4] + y.y * rz_s[5] + y.z * rz_s[6] + y.w * rz_s[7];
            fw[(size_t)b * kT + t] = 0.125f * f;
        }
    }
}

// ---------------------------------------------------------------------------
extern "C" void kernel_launch(void* const* d_in, const int* in_sizes, int n_in,
                              void* d_out, int out_size, void* d_ws, size_t ws_size,
                              hipStream_t stream) {
    const float* query = (const float*)d_in[0];
    const float* mem   = (const float*)d_in[1];
    const float* awc   = (const float*)d_in[3];
    const float* Wq    = (const float*)d_in[5];
    const float* bq    = (const float*)d_in[6];
    const float* Wk    = (const float*)d_in[7];
    const float* bk    = (const float*)d_in[8];
    const float* convw = (const float*)d_in[13];
    const float* Wl    = (const float*)d_in[14];

    float* ws   = (float*)d_ws;
    float* wqe  = ws + OFF_WQE;
    float* cq   = ws + OFF_CQ;
    float* keff = ws + OFF_KEFF;
    float* sc   = ws + OFF_SC;
    float* part = ws + OFF_PART;
    float* zp   = ws + OFF_ZP;

    float* ctx = (float*)d_out;                 // [B,E]
    float* fw  = (float*)d_out + kB * kE;       // [B,T]

    k_prep<<<kB * kH, 256, 0, stream>>>(query, Wq, bq, Wk, bk, Wl, convw, wqe, cq, keff);
    k_scores<<<dim3(kChunks, kB), 256, 0, stream>>>(mem, awc, wqe, cq, keff, sc, part, zp);
    k_final<<<dim3(5, kB), 256, 0, stream>>>(part, zp, sc, ctx, fw);
}